// Round 5
// baseline (2060.948 us; speedup 1.0000x reference)
//
#include <hip/hip_runtime.h>

// V=50000, E=64, B=64, T=1024, F=128, H=128, WIN=3, PAD=1
// K = WIN*E = 192 fused reduction dim; G = 2*3H = 768 projection outputs

typedef __attribute__((ext_vector_type(8))) unsigned short ushort8;
typedef __attribute__((ext_vector_type(8))) short bf16x8;   // MFMA bf16 frag (guide §3)
typedef __attribute__((ext_vector_type(4))) float f32x4;

__device__ __forceinline__ unsigned short f2bf(float f) {
  unsigned int u = __float_as_uint(f);
  u += 0x7fffu + ((u >> 16) & 1u);   // RNE
  return (unsigned short)(u >> 16);
}
__device__ __forceinline__ float bf2f(unsigned short us) {
  return __uint_as_float(((unsigned int)us) << 16);
}

// ---------------------------------------------------------------------------
// K0: CWb[g][k] = bf16( sum_f Wih[g][f]*conv_w[f][k] ), xbias[g] = b_ih[g]+Wih[g]·conv_b
__global__ void k0_fuse(const float* __restrict__ conv_w, const float* __restrict__ conv_b,
                        const float* __restrict__ w_ih_f, const float* __restrict__ b_ih_f,
                        const float* __restrict__ w_ih_b, const float* __restrict__ b_ih_b,
                        unsigned short* __restrict__ CWb, float* __restrict__ xbias) {
  int flat = blockIdx.x * 256 + threadIdx.x;
  if (flat >= 768 * 192) return;
  int g = flat / 192, k = flat % 192;
  const float* wih = (g < 384) ? w_ih_f : w_ih_b;
  int gg = (g < 384) ? g : g - 384;
  float acc = 0.f;
  for (int f = 0; f < 128; ++f) acc += wih[gg * 128 + f] * conv_w[f * 192 + k];
  CWb[g * 192 + k] = f2bf(acc);
  if (k == 0) {
    const float* bih = (g < 384) ? b_ih_f : b_ih_b;
    float bb = bih[gg];
    for (int f = 0; f < 128; ++f) bb += wih[gg * 128 + f] * conv_b[f];
    xbias[g] = bb;
  }
}

// ---------------------------------------------------------------------------
// K1: xp[b][t][g] = bf16( xbias[g] + sum_k A[t][k]*CW[g][k] ) via MFMA bf16.
//     Block = 128t x 128g, K=192. 4 waves in 2x2, wave tile 64x64 (4x4 frags).
__global__ __launch_bounds__(256) void k1_gemm(const int* __restrict__ ipts,
                                               const float* __restrict__ emb,
                                               const unsigned short* __restrict__ CWb,
                                               const float* __restrict__ xbias,
                                               unsigned short* __restrict__ xp) {
  __shared__ __align__(16) unsigned short xs[130][72];    // bf16 emb rows, stride 144B
  __shared__ __align__(16) unsigned short wsb[128][200];  // bf16 CW chunk, stride 400B
  const int bid = blockIdx.x;
  const int gb = bid % 6, tb = bid / 6;
  const int b = tb >> 3, t0 = (tb & 7) << 7, g0 = gb << 7;
  const int tid = threadIdx.x;

  for (int c = tid; c < 130 * 16; c += 256) {   // stage A (gather + f32->bf16)
    int row = c >> 4, cc = c & 15;
    int t = t0 - 1 + row;
    float4 v = make_float4(0.f, 0.f, 0.f, 0.f);
    if (t >= 0 && t < 1024) {
      int tok = ipts[b * 1024 + t];
      v = *reinterpret_cast<const float4*>(emb + (size_t)tok * 64 + cc * 4);
    }
    ushort4 pv;
    pv.x = f2bf(v.x); pv.y = f2bf(v.y); pv.z = f2bf(v.z); pv.w = f2bf(v.w);
    *reinterpret_cast<ushort4*>(&xs[row][cc * 4]) = pv;
  }
  for (int c = tid; c < 128 * 24; c += 256) {   // stage B chunk
    int g = c / 24, cc = c % 24;
    *reinterpret_cast<ushort8*>(&wsb[g][cc * 8]) =
        *reinterpret_cast<const ushort8*>(CWb + (size_t)(g0 + g) * 192 + cc * 8);
  }
  __syncthreads();

  const int lane = tid & 63, wid = tid >> 6;
  const int wy = wid >> 1, wx = wid & 1;
  const int ln15 = lane & 15, lhi = lane >> 4;

  f32x4 acc[4][4];
#pragma unroll
  for (int i = 0; i < 4; ++i)
#pragma unroll
    for (int j = 0; j < 4; ++j) acc[i][j] = (f32x4){0.f, 0.f, 0.f, 0.f};

#pragma unroll
  for (int kk = 0; kk < 6; ++kk) {
    const int w = kk >> 1;                    // k = w*64 + e, never straddles w
    const int e0 = (kk & 1) * 32 + lhi * 8;
    const int k0 = kk * 32 + lhi * 8;
    bf16x8 a[4], bb[4];
#pragma unroll
    for (int i = 0; i < 4; ++i)
      a[i] = *reinterpret_cast<const bf16x8*>(&xs[wy * 64 + i * 16 + ln15 + w][e0]);
#pragma unroll
    for (int j = 0; j < 4; ++j)
      bb[j] = *reinterpret_cast<const bf16x8*>(&wsb[wx * 64 + j * 16 + ln15][k0]);
#pragma unroll
    for (int i = 0; i < 4; ++i)
#pragma unroll
      for (int j = 0; j < 4; ++j)
        acc[i][j] = __builtin_amdgcn_mfma_f32_16x16x32_bf16(a[i], bb[j], acc[i][j], 0, 0, 0);
  }

  float bias[4];
#pragma unroll
  for (int j = 0; j < 4; ++j) bias[j] = xbias[g0 + wx * 64 + j * 16 + ln15];

  unsigned short* outp = xp + (size_t)(b * 1024 + t0 + wy * 64) * 768 + g0 + wx * 64;
#pragma unroll
  for (int i = 0; i < 4; ++i)
#pragma unroll
    for (int r = 0; r < 4; ++r) {
      int m = i * 16 + lhi * 4 + r;           // C/D: col=lane&15, row=(lane>>4)*4+reg
#pragma unroll
      for (int j = 0; j < 4; ++j)
        outp[(size_t)m * 768 + j * 16 + ln15] = f2bf(acc[i][j][r] + bias[j]);
    }
}

// ---------------------------------------------------------------------------
// K2: GRU scan, batched-MFMA formulation.
//     16 blocks = 2 dirs x 4 batch-groups of NB=16. 256 thr = 4 waves.
//     Per step: gh(384x16) = W_hh(384x128) . h(128x16) via mfma_16x16x32_bf16.
//     Wave w owns j-rows [16w,16w+16) and [64+16w,64+16w+16) for ALL 3 gates:
//       24 MFMA/wave/step, W-frags resident in 96 VGPR, r/z/n for each (j,b)
//       land in one lane's C-regs -> register-local gate combine, no LDS reduce.
//     h in LDS as bf16, double-buffered, [k-octet o][b^o (XOR-swz)][8k] -> <=2-way banks.
//     x-gates: per-lane global ushort4 loads prefetched 1 step ahead (xp is
//     L3-resident); per-step sync = lgkmcnt(0) + raw s_barrier (no vmcnt drain).
//     Per-batch len: freeze mask (h holds, acc stops) + clamped row pointer.
__global__ __launch_bounds__(256) void k2_scan(
    const int* __restrict__ seqlen, const float* __restrict__ hidden,
    const float* __restrict__ w_hh_f, const float* __restrict__ b_hh_f,
    const float* __restrict__ w_hh_b, const float* __restrict__ b_hh_b,
    const unsigned short* __restrict__ xp, float* __restrict__ mot) {
  __shared__ __align__(16) unsigned short hb[2][16][16][8];  // [buf][octet][b^o][8k]
  const int tid = threadIdx.x;
  const int dir = blockIdx.x >> 2;
  const int bset = (blockIdx.x & 3) * 16;
  const int lane = tid & 63;
  const int w = tid >> 6;        // wave 0..3
  const int ln = lane & 15;      // = batch col (B-frag n / C col / A row)
  const int lh = lane >> 4;      // k-subgroup / C row-group
  const float* whh = dir ? w_hh_b : w_hh_f;
  const float* bhh = dir ? b_hh_b : b_hh_f;
  const int jb0 = w * 16, jb1 = 64 + w * 16;   // this wave's two M-tile j-bases

  // --- W fragments resident in VGPRs: [tile][gate][kt] ---
  bf16x8 Wf[2][3][4];
#pragma unroll
  for (int tt = 0; tt < 2; ++tt) {
    const int jb = tt ? jb1 : jb0;
#pragma unroll
    for (int g = 0; g < 3; ++g)
#pragma unroll
      for (int kt = 0; kt < 4; ++kt) {
        const float* rp = whh + (size_t)(g * 128 + jb + ln) * 128 + kt * 32 + lh * 8;
        float4 v0 = *reinterpret_cast<const float4*>(rp);
        float4 v1 = *reinterpret_cast<const float4*>(rp + 4);
        bf16x8 f;
        f[0] = (short)f2bf(v0.x); f[1] = (short)f2bf(v0.y);
        f[2] = (short)f2bf(v0.z); f[3] = (short)f2bf(v0.w);
        f[4] = (short)f2bf(v1.x); f[5] = (short)f2bf(v1.y);
        f[6] = (short)f2bf(v1.z); f[7] = (short)f2bf(v1.w);
        Wf[tt][g][kt] = f;
      }
  }

  // --- biases + initial h (per-lane, register-resident) ---
  float bias[2][3][4], hold[2][4], acc[2][4];
#pragma unroll
  for (int tt = 0; tt < 2; ++tt) {
    const int jb = tt ? jb1 : jb0;
#pragma unroll
    for (int g = 0; g < 3; ++g)
#pragma unroll
      for (int r = 0; r < 4; ++r) bias[tt][g][r] = bhh[g * 128 + jb + lh * 4 + r];
#pragma unroll
    for (int r = 0; r < 4; ++r) {
      hold[tt][r] = hidden[(size_t)(dir * 64 + bset + ln) * 128 + jb + lh * 4 + r];
      acc[tt][r] = 0.f;
    }
  }

  // --- stage h0 into hb[0]: thread (o=tid>>4, b=tid&15) packs 8 k-values ---
  {
    const int o = tid >> 4, bb = tid & 15;
    const float* hp = hidden + (size_t)(dir * 64 + bset + bb) * 128 + o * 8;
    float4 v0 = *reinterpret_cast<const float4*>(hp);
    float4 v1 = *reinterpret_cast<const float4*>(hp + 4);
    ushort8 f;
    f[0] = f2bf(v0.x); f[1] = f2bf(v0.y); f[2] = f2bf(v0.z); f[3] = f2bf(v0.w);
    f[4] = f2bf(v1.x); f[5] = f2bf(v1.y); f[6] = f2bf(v1.z); f[7] = f2bf(v1.w);
    *reinterpret_cast<ushort8*>(&hb[0][o][(bb ^ o) & 15][0]) = f;
  }

  // --- lengths ---
  const int lb = seqlen[bset + ln];   // this lane's batch length
  int ml = 0;
  for (int i = 0; i < 16; ++i) ml = max(ml, seqlen[bset + i]);  // uniform

  // --- x prefetch for t=0 ---
  const unsigned short* xpb = xp + (size_t)(bset + ln) * (1024 * 768) + dir * 384;
  int tr = dir ? (lb - 1) : 0;        // xp row for the NEXT consume
  ushort4 xv[2][3];
#pragma unroll
  for (int tt = 0; tt < 2; ++tt)
#pragma unroll
    for (int g = 0; g < 3; ++g)
      xv[tt][g] = *reinterpret_cast<const ushort4*>(
          xpb + (size_t)tr * 768 + g * 128 + (tt ? jb1 : jb0) + lh * 4);

  __syncthreads();

  for (int t = 0; t < ml; ++t) {
    const int cur = t & 1, nxt = cur ^ 1;

    // 1. convert current x to f32 (frees xv for next prefetch)
    float xf[2][3][4];
#pragma unroll
    for (int tt = 0; tt < 2; ++tt)
#pragma unroll
      for (int g = 0; g < 3; ++g) {
        xf[tt][g][0] = bf2f(xv[tt][g].x); xf[tt][g][1] = bf2f(xv[tt][g].y);
        xf[tt][g][2] = bf2f(xv[tt][g].z); xf[tt][g][3] = bf2f(xv[tt][g].w);
      }

    // 2. advance row (clamped per lane) + issue next step's 6 loads
    {
      const int sel = (t + 1 < lb) ? 1 : 0;
      tr += dir ? -sel : sel;
#pragma unroll
      for (int tt = 0; tt < 2; ++tt)
#pragma unroll
        for (int g = 0; g < 3; ++g)
          xv[tt][g] = *reinterpret_cast<const ushort4*>(
              xpb + (size_t)tr * 768 + g * 128 + (tt ? jb1 : jb0) + lh * 4);
    }

    // 3. B-frags from h-LDS, 24 MFMA
    bf16x8 Bf[4];
#pragma unroll
    for (int kt = 0; kt < 4; ++kt) {
      const int o = kt * 4 + lh;
      Bf[kt] = *reinterpret_cast<const bf16x8*>(&hb[cur][o][(ln ^ o) & 15][0]);
    }
    f32x4 C[2][3];
#pragma unroll
    for (int tt = 0; tt < 2; ++tt)
#pragma unroll
      for (int g = 0; g < 3; ++g) {
        f32x4 c = (f32x4){0.f, 0.f, 0.f, 0.f};
#pragma unroll
        for (int kt = 0; kt < 4; ++kt)
          c = __builtin_amdgcn_mfma_f32_16x16x32_bf16(Wf[tt][g][kt], Bf[kt], c, 0, 0, 0);
        C[tt][g] = c;
      }

    // 4. register-local gate combine (+freeze mask), 5. publish h(t+1)
    const bool msk = (t < lb);
#pragma unroll
    for (int tt = 0; tt < 2; ++tt) {
      const int jb = tt ? jb1 : jb0;
      unsigned int pk0, pk1;
      {
        unsigned short hpk[4];
#pragma unroll
        for (int r = 0; r < 4; ++r) {
          float rr = 1.f / (1.f + __expf(-(xf[tt][0][r] + C[tt][0][r] + bias[tt][0][r])));
          float zz = 1.f / (1.f + __expf(-(xf[tt][1][r] + C[tt][1][r] + bias[tt][1][r])));
          float na = xf[tt][2][r] + rr * (C[tt][2][r] + bias[tt][2][r]);
          float e2 = __expf(2.f * na);
          float nn = (e2 - 1.f) / (e2 + 1.f);
          float hn = (1.f - zz) * nn + zz * hold[tt][r];
          hn = msk ? hn : hold[tt][r];
          acc[tt][r] += msk ? hn : 0.f;
          hold[tt][r] = hn;
          hpk[r] = f2bf(hn);
        }
        pk0 = (unsigned int)hpk[0] | ((unsigned int)hpk[1] << 16);
        pk1 = (unsigned int)hpk[2] | ((unsigned int)hpk[3] << 16);
      }
      const int jq = jb + lh * 4;
      const int o = jq >> 3, jo = jq & 7;
      uint2* dst = reinterpret_cast<uint2*>(&hb[nxt][o][(ln ^ o) & 15][jo]);
      *dst = make_uint2(pk0, pk1);
    }

    // 6. per-step sync: ds ops drained, loads stay in flight
    asm volatile("s_waitcnt lgkmcnt(0)" ::: "memory");
    __builtin_amdgcn_s_barrier();
    __builtin_amdgcn_sched_barrier(0);
  }

  // --- masked mean -> mot[b][dir*128 + j] ---
#pragma unroll
  for (int tt = 0; tt < 2; ++tt) {
    const int jb = tt ? jb1 : jb0;
#pragma unroll
    for (int r = 0; r < 4; ++r)
      mot[(size_t)(bset + ln) * 256 + dir * 128 + jb + lh * 4 + r] =
          acc[tt][r] / (float)lb;
  }
}

// ---------------------------------------------------------------------------
// K3: out[b] = sigmoid(dot(mot[b], lin_w) + lin_b)
__global__ void k3_final(const float* __restrict__ mot, const float* __restrict__ lin_w,
                         const float* __restrict__ lin_b, float* __restrict__ out) {
  int tid = threadIdx.x;
  int b = tid >> 2, part = tid & 3;
  float s = 0.f;
  for (int i = 0; i < 64; ++i) s += mot[b * 256 + part * 64 + i] * lin_w[part * 64 + i];
  s += __shfl_xor(s, 1);
  s += __shfl_xor(s, 2);
  if (part == 0) out[b] = 1.f / (1.f + __expf(-(s + lin_b[0])));
}

// ---------------------------------------------------------------------------
extern "C" void kernel_launch(void* const* d_in, const int* in_sizes, int n_in,
                              void* d_out, int out_size, void* d_ws, size_t ws_size,
                              hipStream_t stream) {
  const int*   ipts    = (const int*)d_in[0];
  const int*   seqlen  = (const int*)d_in[1];
  const float* hidden  = (const float*)d_in[2];
  const float* emb     = (const float*)d_in[3];
  const float* conv_w  = (const float*)d_in[4];
  const float* conv_b  = (const float*)d_in[5];
  const float* w_ih_f  = (const float*)d_in[6];
  const float* w_hh_f  = (const float*)d_in[7];
  const float* b_ih_f  = (const float*)d_in[8];
  const float* b_hh_f  = (const float*)d_in[9];
  const float* w_ih_b  = (const float*)d_in[10];
  const float* w_hh_b  = (const float*)d_in[11];
  const float* b_ih_b  = (const float*)d_in[12];
  const float* b_hh_b  = (const float*)d_in[13];
  const float* lin_w   = (const float*)d_in[14];
  const float* lin_b   = (const float*)d_in[15];

  char* ws = (char*)d_ws;
  unsigned short* CWb = (unsigned short*)(ws);           // 294,912 B
  float* xbias = (float*)(ws + 294912);                  // 3,072 B
  float* mot   = (float*)(ws + 298240);                  // 65,536 B
  unsigned short* xp = (unsigned short*)(ws + 1048576);  // 100,663,296 B (bf16)
  float* out = (float*)d_out;

  hipLaunchKernelGGL(k0_fuse, dim3(576), dim3(256), 0, stream,
                     conv_w, conv_b, w_ih_f, b_ih_f, w_ih_b, b_ih_b, CWb, xbias);
  hipLaunchKernelGGL(k1_gemm, dim3(3072), dim3(256), 0, stream,
                     ipts, emb, CWb, xbias, xp);
  hipLaunchKernelGGL(k2_scan, dim3(16), dim3(256), 0, stream,
                     seqlen, hidden, w_hh_f, b_hh_f, w_hh_b, b_hh_b, xp, mot);
  hipLaunchKernelGGL(k3_final, dim3(1), dim3(256), 0, stream, mot, lin_w, lin_b, out);
}

// Round 6
// 899.731 us; speedup vs baseline: 2.2906x; 2.2906x over previous
//
#include <hip/hip_runtime.h>

// V=50000, E=64, B=64, T=1024, F=128, H=128, WIN=3, PAD=1
// K = WIN*E = 192 fused reduction dim; G = 2*3H = 768 projection outputs

typedef __attribute__((ext_vector_type(8))) unsigned short ushort8;
typedef __attribute__((ext_vector_type(8))) short bf16x8;   // MFMA bf16 frag (guide §3)
typedef __attribute__((ext_vector_type(4))) float f32x4;
typedef _Float16 f16x2 __attribute__((ext_vector_type(2)));

__device__ __forceinline__ unsigned short f2bf(float f) {
  unsigned int u = __float_as_uint(f);
  u += 0x7fffu + ((u >> 16) & 1u);   // RNE
  return (unsigned short)(u >> 16);
}
__device__ __forceinline__ float bf2f(unsigned short us) {
  return __uint_as_float(((unsigned int)us) << 16);
}
__device__ __forceinline__ unsigned short f2h_bits(float f) {
  _Float16 h = (_Float16)f;
  return __builtin_bit_cast(unsigned short, h);
}
__device__ __forceinline__ void gload_lds16(const void* g, void* l) {
  __builtin_amdgcn_global_load_lds((const __attribute__((address_space(1))) void*)g,
                                   (__attribute__((address_space(3))) void*)l, 16, 0, 0);
}
// sum over the 4 lanes of a DPP quad (k-quarters) — VALU only, no LDS
__device__ __forceinline__ float quad_red(float x) {
  int xi = __float_as_int(x);
  x += __int_as_float(__builtin_amdgcn_update_dpp(0, xi, 0xB1, 0xF, 0xF, true));  // xor 1
  xi = __float_as_int(x);
  x += __int_as_float(__builtin_amdgcn_update_dpp(0, xi, 0x4E, 0xF, 0xF, true));  // xor 2
  return x;
}

#if __has_builtin(__builtin_amdgcn_fdot2)
#define FDOT2(a, b, c) __builtin_amdgcn_fdot2((a), (b), (c), false)
#else
#define FDOT2(a, b, c) ((float)(a).x * (float)(b).x + (float)(a).y * (float)(b).y + (c))
#endif

// ---------------------------------------------------------------------------
// K0: CWb[g][k] = bf16( sum_f Wih[g][f]*conv_w[f][k] ), xbias[g] = b_ih[g]+Wih[g]·conv_b
__global__ void k0_fuse(const float* __restrict__ conv_w, const float* __restrict__ conv_b,
                        const float* __restrict__ w_ih_f, const float* __restrict__ b_ih_f,
                        const float* __restrict__ w_ih_b, const float* __restrict__ b_ih_b,
                        unsigned short* __restrict__ CWb, float* __restrict__ xbias) {
  int flat = blockIdx.x * 256 + threadIdx.x;
  if (flat >= 768 * 192) return;
  int g = flat / 192, k = flat % 192;
  const float* wih = (g < 384) ? w_ih_f : w_ih_b;
  int gg = (g < 384) ? g : g - 384;
  float acc = 0.f;
  for (int f = 0; f < 128; ++f) acc += wih[gg * 128 + f] * conv_w[f * 192 + k];
  CWb[g * 192 + k] = f2bf(acc);
  if (k == 0) {
    const float* bih = (g < 384) ? b_ih_f : b_ih_b;
    float bb = bih[gg];
    for (int f = 0; f < 128; ++f) bb += wih[gg * 128 + f] * conv_b[f];
    xbias[g] = bb;
  }
}

// ---------------------------------------------------------------------------
// K1: xp[b][t][g] = bf16( xbias[g] + sum_k A[t][k]*CW[g][k] ) via MFMA bf16.
//     Block = 128t x 128g, K=192. 4 waves in 2x2, wave tile 64x64 (4x4 frags).
__global__ __launch_bounds__(256) void k1_gemm(const int* __restrict__ ipts,
                                               const float* __restrict__ emb,
                                               const unsigned short* __restrict__ CWb,
                                               const float* __restrict__ xbias,
                                               unsigned short* __restrict__ xp) {
  __shared__ __align__(16) unsigned short xs[130][72];    // bf16 emb rows, stride 144B
  __shared__ __align__(16) unsigned short wsb[128][200];  // bf16 CW chunk, stride 400B
  const int bid = blockIdx.x;
  const int gb = bid % 6, tb = bid / 6;
  const int b = tb >> 3, t0 = (tb & 7) << 7, g0 = gb << 7;
  const int tid = threadIdx.x;

  for (int c = tid; c < 130 * 16; c += 256) {   // stage A (gather + f32->bf16)
    int row = c >> 4, cc = c & 15;
    int t = t0 - 1 + row;
    float4 v = make_float4(0.f, 0.f, 0.f, 0.f);
    if (t >= 0 && t < 1024) {
      int tok = ipts[b * 1024 + t];
      v = *reinterpret_cast<const float4*>(emb + (size_t)tok * 64 + cc * 4);
    }
    ushort4 pv;
    pv.x = f2bf(v.x); pv.y = f2bf(v.y); pv.z = f2bf(v.z); pv.w = f2bf(v.w);
    *reinterpret_cast<ushort4*>(&xs[row][cc * 4]) = pv;
  }
  for (int c = tid; c < 128 * 24; c += 256) {   // stage B chunk
    int g = c / 24, cc = c % 24;
    *reinterpret_cast<ushort8*>(&wsb[g][cc * 8]) =
        *reinterpret_cast<const ushort8*>(CWb + (size_t)(g0 + g) * 192 + cc * 8);
  }
  __syncthreads();

  const int lane = tid & 63, wid = tid >> 6;
  const int wy = wid >> 1, wx = wid & 1;
  const int ln15 = lane & 15, lhi = lane >> 4;

  f32x4 acc[4][4];
#pragma unroll
  for (int i = 0; i < 4; ++i)
#pragma unroll
    for (int j = 0; j < 4; ++j) acc[i][j] = (f32x4){0.f, 0.f, 0.f, 0.f};

#pragma unroll
  for (int kk = 0; kk < 6; ++kk) {
    const int w = kk >> 1;                    // k = w*64 + e, never straddles w
    const int e0 = (kk & 1) * 32 + lhi * 8;
    const int k0 = kk * 32 + lhi * 8;
    bf16x8 a[4], bb[4];
#pragma unroll
    for (int i = 0; i < 4; ++i)
      a[i] = *reinterpret_cast<const bf16x8*>(&xs[wy * 64 + i * 16 + ln15 + w][e0]);
#pragma unroll
    for (int j = 0; j < 4; ++j)
      bb[j] = *reinterpret_cast<const bf16x8*>(&wsb[wx * 64 + j * 16 + ln15][k0]);
#pragma unroll
    for (int i = 0; i < 4; ++i)
#pragma unroll
      for (int j = 0; j < 4; ++j)
        acc[i][j] = __builtin_amdgcn_mfma_f32_16x16x32_bf16(a[i], bb[j], acc[i][j], 0, 0, 0);
  }

  float bias[4];
#pragma unroll
  for (int j = 0; j < 4; ++j) bias[j] = xbias[g0 + wx * 64 + j * 16 + ln15];

  unsigned short* outp = xp + (size_t)(b * 1024 + t0 + wy * 64) * 768 + g0 + wx * 64;
#pragma unroll
  for (int i = 0; i < 4; ++i)
#pragma unroll
    for (int r = 0; r < 4; ++r) {
      int m = i * 16 + lhi * 4 + r;           // C/D: col=lane&15, row=(lane>>4)*4+reg
#pragma unroll
      for (int j = 0; j < 4; ++j)
        outp[(size_t)m * 768 + j * 16 + ln15] = f2bf(acc[i][j][r] + bias[j]);
    }
}

// ---------------------------------------------------------------------------
// K2: GRU scan. One block (512 thr) per BATCH: waves 0-3 = forward dir,
//     waves 4-7 = backward dir (same len -> lockstep). 64 blocks.
//     Within a dir (256 thr): lane group of 4 owns j-pair {2p,2p+1}; lane
//     quarter q covers k in [32q,32q+32). Weights f16x2 in VGPRs (96),
//     h f16 in double-buffered LDS (64B/lane reads, 2-way banks max),
//     v_dot2_f32_f16 dots, DPP quad-reduce (VALU, no LDS), gate combine
//     split by lane parity, h' written by q=0 (j even) / q=2 (j odd).
//     x staged per-dir in LDS tiles of 16 steps via global_load_lds;
//     per-step sync = lgkmcnt(0) + raw s_barrier; vmcnt(0) at tile edge only.
__global__ __launch_bounds__(512) void k2_scan(
    const int* __restrict__ seqlen, const float* __restrict__ hidden,
    const float* __restrict__ w_hh_f, const float* __restrict__ b_hh_f,
    const float* __restrict__ w_hh_b, const float* __restrict__ b_hh_b,
    const unsigned short* __restrict__ xp, float* __restrict__ mot) {
  __shared__ __align__(16) unsigned short hb[2][2][128];      // [dir][buf][j] f16
  __shared__ __align__(16) unsigned short xt[2][2][16][384];  // [dir][buf][step][gate]
  const int tid = threadIdx.x;
  const int dir = tid >> 8;
  const int ltid = tid & 255;
  const int b = blockIdx.x;
  const int p = ltid >> 2;          // j-pair 0..63
  const int q = ltid & 3;           // k-quarter
  const int jj = q >> 1;            // which j this lane combines
  const int j = 2 * p + jj;
  const float* whh = dir ? w_hh_b : w_hh_f;
  const float* bhh = dir ? b_hh_b : b_hh_f;

  // --- weights: 3 gates x 2 j x 32 k as f16 pairs (96 VGPR) ---
  f16x2 Wf[3][2][16];
#pragma unroll
  for (int g = 0; g < 3; ++g)
#pragma unroll
    for (int jr = 0; jr < 2; ++jr) {
      const float* rp = whh + (size_t)(g * 128 + 2 * p + jr) * 128 + q * 32;
#pragma unroll
      for (int c = 0; c < 8; ++c) {
        float4 v = *reinterpret_cast<const float4*>(rp + 4 * c);
        f16x2 lo, hi;
        lo.x = (_Float16)v.x; lo.y = (_Float16)v.y;
        hi.x = (_Float16)v.z; hi.y = (_Float16)v.w;
        Wf[g][jr][2 * c] = lo; Wf[g][jr][2 * c + 1] = hi;
      }
    }

  const int len = seqlen[b];   // block-uniform: fwd+bwd of the SAME batch
  float h_old = hidden[(size_t)(dir * 64 + b) * 128 + j];
  if (ltid < 128) hb[dir][0][ltid] = f2h_bits(hidden[(size_t)(dir * 64 + b) * 128 + ltid]);
  const float bh0 = bhh[j], bh1 = bhh[128 + j], bh2 = bhh[256 + j];
  float acc = 0.f;

  // --- prologue: stage x tile 0 (16 steps x 768B) for this dir ---
  const unsigned short* xpb = xp + (size_t)b * (1024 * 768) + dir * 384;
  {
    unsigned short* base = &xt[dir][0][0][0];
#pragma unroll
    for (int i = 0; i < 3; ++i) {
      const int c = i * 256 + ltid;          // 16B-chunk 0..767
      const int st = c / 48, cc = c - st * 48;
      unsigned short* ldst = base + (size_t)(i * 256 + (ltid & ~63)) * 8;
      const int row = dir ? (len - 1 - st) : st;
      gload_lds16(xpb + (size_t)row * 768 + cc * 8, ldst);
    }
  }
  __syncthreads();   // drains vmcnt (tile 0 ready) + lds init

  for (int t = 0; t < len; ++t) {
    const int s = t & 15;
    const int buf = (t >> 4) & 1;
    const int cur = t & 1;

    // x gates for this lane's j-pair (b32 = both j's bf16; broadcast 4 lanes)
    const unsigned short* xrow = &xt[dir][buf][s][0];
    const unsigned int xw0 = *reinterpret_cast<const unsigned int*>(&xrow[2 * p]);
    const unsigned int xw1 = *reinterpret_cast<const unsigned int*>(&xrow[128 + 2 * p]);
    const unsigned int xw2 = *reinterpret_cast<const unsigned int*>(&xrow[256 + 2 * p]);

    // tile boundary: kick off next tile's loads into the other buffer
    if (s == 0 && t + 16 < len) {
      unsigned short* base = &xt[dir][buf ^ 1][0][0];
#pragma unroll
      for (int i = 0; i < 3; ++i) {
        const int c = i * 256 + ltid;
        const int st = c / 48, cc = c - st * 48;
        const int at = t + 16 + st;
        unsigned short* ldst = base + (size_t)(i * 256 + (ltid & ~63)) * 8;
        if (at < len) {
          const int row = dir ? (len - 1 - at) : at;
          gload_lds16(xpb + (size_t)row * 768 + cc * 8, ldst);
        }
      }
    }

    // h quarter: 4 x ds_read_b128 (2-way banks max)
    unsigned int hw[16];
#pragma unroll
    for (int c = 0; c < 4; ++c) {
      uint4 v = *reinterpret_cast<const uint4*>(&hb[dir][cur][32 * q + 8 * c]);
      hw[4 * c] = v.x; hw[4 * c + 1] = v.y; hw[4 * c + 2] = v.z; hw[4 * c + 3] = v.w;
    }

    float p00 = 0.f, p01 = 0.f, p10 = 0.f, p11 = 0.f, p20 = 0.f, p21 = 0.f;
#pragma unroll
    for (int d = 0; d < 16; ++d) {
      f16x2 h2 = __builtin_bit_cast(f16x2, hw[d]);
      p00 = FDOT2(Wf[0][0][d], h2, p00);
      p01 = FDOT2(Wf[0][1][d], h2, p01);
      p10 = FDOT2(Wf[1][0][d], h2, p10);
      p11 = FDOT2(Wf[1][1][d], h2, p11);
      p20 = FDOT2(Wf[2][0][d], h2, p20);
      p21 = FDOT2(Wf[2][1][d], h2, p21);
    }
    // sum k-quarters across the DPP quad (VALU only)
    p00 = quad_red(p00); p01 = quad_red(p01);
    p10 = quad_red(p10); p11 = quad_red(p11);
    p20 = quad_red(p20); p21 = quad_red(p21);

    // gate combine for this lane's j (lane parity picks the pair member)
    const float hr = jj ? p01 : p00;
    const float hz = jj ? p11 : p10;
    const float hn = jj ? p21 : p20;
    const float xr = bf2f((unsigned short)(xw0 >> (16 * jj)));
    const float xz = bf2f((unsigned short)(xw1 >> (16 * jj)));
    const float xn = bf2f((unsigned short)(xw2 >> (16 * jj)));
    const float r = 1.f / (1.f + __expf(-(xr + hr + bh0)));
    const float z = 1.f / (1.f + __expf(-(xz + hz + bh1)));
    const float na = xn + r * (hn + bh2);
    const float e2 = __expf(2.f * na);
    const float n = (e2 - 1.f) / (e2 + 1.f);
    const float hnew = (1.f - z) * n + z * h_old;
    acc += hnew;
    h_old = hnew;
    if ((q & 1) == 0) hb[dir][cur ^ 1][j] = f2h_bits(hnew);   // publish h(t+1)

    if (((t + 1) & 15) == 0) asm volatile("s_waitcnt vmcnt(0)" ::: "memory");
    asm volatile("s_waitcnt lgkmcnt(0)" ::: "memory");
    __builtin_amdgcn_s_barrier();
    __builtin_amdgcn_sched_barrier(0);
  }
  if ((q & 1) == 0) mot[(size_t)b * 256 + dir * 128 + j] = acc / (float)len;
}

// ---------------------------------------------------------------------------
// K3: out[b] = sigmoid(dot(mot[b], lin_w) + lin_b)
__global__ void k3_final(const float* __restrict__ mot, const float* __restrict__ lin_w,
                         const float* __restrict__ lin_b, float* __restrict__ out) {
  int tid = threadIdx.x;
  int b = tid >> 2, part = tid & 3;
  float s = 0.f;
  for (int i = 0; i < 64; ++i) s += mot[b * 256 + part * 64 + i] * lin_w[part * 64 + i];
  s += __shfl_xor(s, 1);
  s += __shfl_xor(s, 2);
  if (part == 0) out[b] = 1.f / (1.f + __expf(-(s + lin_b[0])));
}

// ---------------------------------------------------------------------------
extern "C" void kernel_launch(void* const* d_in, const int* in_sizes, int n_in,
                              void* d_out, int out_size, void* d_ws, size_t ws_size,
                              hipStream_t stream) {
  const int*   ipts    = (const int*)d_in[0];
  const int*   seqlen  = (const int*)d_in[1];
  const float* hidden  = (const float*)d_in[2];
  const float* emb     = (const float*)d_in[3];
  const float* conv_w  = (const float*)d_in[4];
  const float* conv_b  = (const float*)d_in[5];
  const float* w_ih_f  = (const float*)d_in[6];
  const float* w_hh_f  = (const float*)d_in[7];
  const float* b_ih_f  = (const float*)d_in[8];
  const float* b_hh_f  = (const float*)d_in[9];
  const float* w_ih_b  = (const float*)d_in[10];
  const float* w_hh_b  = (const float*)d_in[11];
  const float* b_ih_b  = (const float*)d_in[12];
  const float* b_hh_b  = (const float*)d_in[13];
  const float* lin_w   = (const float*)d_in[14];
  const float* lin_b   = (const float*)d_in[15];

  char* ws = (char*)d_ws;
  unsigned short* CWb = (unsigned short*)(ws);           // 294,912 B
  float* xbias = (float*)(ws + 294912);                  // 3,072 B
  float* mot   = (float*)(ws + 298240);                  // 65,536 B
  unsigned short* xp = (unsigned short*)(ws + 1048576);  // 100,663,296 B (bf16)
  float* out = (float*)d_out;

  hipLaunchKernelGGL(k0_fuse, dim3(576), dim3(256), 0, stream,
                     conv_w, conv_b, w_ih_f, b_ih_f, w_ih_b, b_ih_b, CWb, xbias);
  hipLaunchKernelGGL(k1_gemm, dim3(3072), dim3(256), 0, stream,
                     ipts, emb, CWb, xbias, xp);
  hipLaunchKernelGGL(k2_scan, dim3(64), dim3(512), 0, stream,
                     seqlen, hidden, w_hh_f, b_hh_f, w_hh_b, b_hh_b, xp, mot);
  hipLaunchKernelGGL(k3_final, dim3(1), dim3(256), 0, stream, mot, lin_w, lin_b, out);
}